// Round 9
// baseline (240.815 us; speedup 1.0000x reference)
//
#include <hip/hip_runtime.h>
#include <hip/hip_bf16.h>

// ---------------------------------------------------------------------------
// HessianCompatibleMultiHeadAttention on MI355X (gfx950).
// Inputs fp32, output fp32. Internal bf16 MFMA.
// B=2, S=2048, D=1024, H=16, Dk=64.
//   cvt_all:      x, wq, wk, wv, wo  -> bf16
//   gemm_bt<128>: qkv = x_bf @ W^T   (z=0 Q pre-scaled by 0.125*log2e)
//                 [R6-proven BK=32 version; BK=64 regressed -> reverted]
//   transpose_v:  V plane -> V^T [bh][64][2048]
//   attn5:        flash attention, q-tile 128, S^T form, no-max exp2 softmax,
//                 register-double-buffered K/V staging (latency hidden behind
//                 a full tile of compute), dedicated wave-private P region
//                 -> 2 barriers/tile instead of 3.
//   gemm_bt<64>:  out = ab @ Wo^T + b_o  (fp32 out, 512 blocks)
// ---------------------------------------------------------------------------

typedef __bf16 bf16x8 __attribute__((ext_vector_type(8)));
typedef float f32x4 __attribute__((ext_vector_type(4)));

__device__ __forceinline__ unsigned short f2bf(float f) {
  union { float f; unsigned int u; } c; c.f = f;
  unsigned int u = c.u;
  return (unsigned short)((u + 0x7FFFu + ((u >> 16) & 1u)) >> 16);
}

// pack two fp32 -> two bf16 (round-half-up) in 3 VALU ops
__device__ __forceinline__ unsigned int pk2bf(float a, float b) {
  union { float f; unsigned int u; } x, y;
  x.f = a; y.f = b;
  return __builtin_amdgcn_perm(y.u + 0x8000u, x.u + 0x8000u, 0x07060302u);
}

__device__ __forceinline__ bf16x8 ld_frag(const unsigned short* p) {
  union { uint4 u; bf16x8 b; } c;
  c.u = *(const uint4*)p;   // 16B aligned -> ds_read_b128
  return c.b;
}

__device__ __forceinline__ uint4 cvt8(const float* __restrict__ p) {
  float4 a = *(const float4*)p;
  float4 b = *(const float4*)(p + 4);
  union { uint4 u; unsigned short s[8]; } r;
  r.s[0] = f2bf(a.x); r.s[1] = f2bf(a.y); r.s[2] = f2bf(a.z); r.s[3] = f2bf(a.w);
  r.s[4] = f2bf(b.x); r.s[5] = f2bf(b.y); r.s[6] = f2bf(b.z); r.s[7] = f2bf(b.w);
  return r.u;
}

// async global->LDS, 16B per lane (lds dest = wave-uniform base + lane*16)
typedef __attribute__((address_space(1))) const unsigned int as1_u32;
typedef __attribute__((address_space(3))) unsigned int as3_u32;
__device__ __forceinline__ void async16(const unsigned short* g,
                                        unsigned short* l) {
  __builtin_amdgcn_global_load_lds(
      (as1_u32*)(unsigned long long)g,
      (as3_u32*)(unsigned int)(unsigned long long)l, 16, 0, 0);
}

// ---------------------------------------------------------------------------
// fp32 -> bf16 conversion (memory-bound). grid (2048, 5).
// ---------------------------------------------------------------------------
__global__ __launch_bounds__(256) void cvt_all(
    const float* __restrict__ s0, const float* __restrict__ s1,
    const float* __restrict__ s2, const float* __restrict__ s3,
    const float* __restrict__ s4,
    unsigned short* __restrict__ d0, unsigned short* __restrict__ d1,
    unsigned short* __restrict__ d2, unsigned short* __restrict__ d3,
    unsigned short* __restrict__ d4) {
  const float* srcs[5] = {s0, s1, s2, s3, s4};
  unsigned short* dsts[5] = {d0, d1, d2, d3, d4};
  const int ns[5] = {4194304, 1048576, 1048576, 1048576, 1048576};
  const int y = blockIdx.y;
  const int idx = (blockIdx.x * 256 + threadIdx.x) * 8;
  if (idx >= ns[y]) return;
  *(uint4*)(dsts[y] + idx) = cvt8(srcs[y] + idx);
}

// ---------------------------------------------------------------------------
// GEMM [R6-proven]: C[m][n] = scl * sum_k A[m][k] W[n][k] (+ bias[n]).
// N=1024, K=1024. BN=128, BK=32, 256 thr.
// BM=128: 4 waves 2x2 of 64x64 (qkv path, grid (8,32,3)).
// BM=64:  4 waves 1x4, wave = 64m x 32n (out path, grid (8,64,1)).
// Staging: global_load_lds w=16; unpadded LDS [row][32], k-chunk XOR swizzle.
// ---------------------------------------------------------------------------
template <int BM, bool OUT_F32>
__global__ __launch_bounds__(256) void gemm_bt(
    const unsigned short* __restrict__ A,
    const unsigned short* __restrict__ w0,
    const unsigned short* __restrict__ w1,
    const unsigned short* __restrict__ w2,
    const float* __restrict__ bias,
    void* __restrict__ outraw, float z0scale) {
  constexpr int NT = (BM == 128) ? 4 : 2;
  const int z = blockIdx.z;
  const unsigned short* W = (z == 0) ? w0 : ((z == 1) ? w1 : w2);
  const float scl = (z == 0) ? z0scale : 1.0f;

  __shared__ unsigned short a_lds[BM * 32];
  __shared__ unsigned short b_lds[128 * 32];

  const int tid = threadIdx.x;
  const int wave = tid >> 6, lane = tid & 63;
  const int quad = lane >> 4, l16 = lane & 15;
  const int wm = (BM == 128) ? (wave >> 1) * 64 : 0;
  const int wn = (BM == 128) ? (wave & 1) * 64 : wave * 32;
  const int bm = blockIdx.y * BM, bn = blockIdx.x * 128;

  const int rl = lane >> 2;   // 0..15
  const int kc = (lane & 3) ^ (rl & 3) ^ ((rl >> 2) & 3);
  const int arow = (BM == 128) ? (wave * 32 + rl) : (wave * 16 + rl);
  const unsigned short* ga = A + (size_t)(bm + arow) * 1024 + kc * 8;
  const unsigned short* gb = W + (size_t)(bn + wave * 32 + rl) * 1024 + kc * 8;
  unsigned short* la = &a_lds[((BM == 128) ? wave * 32 : wave * 16) * 32];
  unsigned short* lb = &b_lds[wave * 32 * 32];

  const int rsw8 = ((l16 & 3) ^ ((l16 >> 2) & 3)) * 8;

  f32x4 acc[4][NT] = {};

  for (int k0 = 0; k0 < 1024; k0 += 32) {
    async16(ga, la);
    if (BM == 128) async16(ga + 16 * 1024, la + 16 * 32);
    async16(gb, lb);
    async16(gb + 16 * 1024, lb + 16 * 32);
    ga += 32; gb += 32;
    __syncthreads();

    bf16x8 af[4], bfr[NT];
#pragma unroll
    for (int t = 0; t < 4; ++t)
      af[t] = ld_frag(&a_lds[(wm + t * 16 + l16) * 32 + ((quad * 8) ^ rsw8)]);
#pragma unroll
    for (int t = 0; t < NT; ++t)
      bfr[t] = ld_frag(&b_lds[(wn + t * 16 + l16) * 32 + ((quad * 8) ^ rsw8)]);
#pragma unroll
    for (int mt = 0; mt < 4; ++mt)
#pragma unroll
      for (int nt = 0; nt < NT; ++nt)
        acc[mt][nt] = __builtin_amdgcn_mfma_f32_16x16x32_bf16(
            af[mt], bfr[nt], acc[mt][nt], 0, 0, 0);
    __syncthreads();
  }

  // Epilogue: C/D layout col = lane&15, row = quad*4 + reg  [m89-verified]
#pragma unroll
  for (int nt = 0; nt < NT; ++nt) {
    const int n = bn + wn + nt * 16 + l16;
    const float bv = bias ? bias[n] : 0.0f;
#pragma unroll
    for (int mt = 0; mt < 4; ++mt)
#pragma unroll
      for (int r = 0; r < 4; ++r) {
        const int m = bm + wm + mt * 16 + quad * 4 + r;
        const float v = acc[mt][nt][r] * scl + bv;
        if (OUT_F32)
          ((float*)outraw)[(size_t)z * 4096 * 1024 + (size_t)m * 1024 + n] = v;
        else
          ((unsigned short*)outraw)[(size_t)z * 4096 * 1024 +
                                    (size_t)m * 1024 + n] = f2bf(v);
      }
  }
}

// ---------------------------------------------------------------------------
// V plane [4096][1024] -> V^T [32 bh][64 d][2048 s]. grid (32, 32).
// ---------------------------------------------------------------------------
__global__ __launch_bounds__(256) void transpose_v(
    const unsigned short* __restrict__ v, unsigned short* __restrict__ vt) {
  const int st0 = blockIdx.x * 64;
  const int bh = blockIdx.y, b = bh >> 4, h = bh & 15;
  __shared__ unsigned short t[64 * 72];
  const int tid = threadIdx.x;
#pragma unroll
  for (int it = 0; it < 2; ++it) {
    const int c = it * 256 + tid;
    const int row = c >> 3, c8 = (c & 7) * 8;
    *(uint4*)&t[row * 72 + c8] =
        *(const uint4*)(v + (size_t)(b * 2048 + st0 + row) * 1024 + h * 64 + c8);
  }
  __syncthreads();
#pragma unroll
  for (int it = 0; it < 2; ++it) {
    const int c = it * 256 + tid;
    const int drow = c >> 3, s8 = (c & 7) * 8;
    union { uint4 u; unsigned short e[8]; } o;
#pragma unroll
    for (int j = 0; j < 8; ++j) o.e[j] = t[(s8 + j) * 72 + drow];
    *(uint4*)(vt + ((size_t)bh * 64 + drow) * 2048 + st0 + s8) = o.u;
  }
}

// ---------------------------------------------------------------------------
// Flash attention v5. q-tile 128, S^T form, no-max exp2 softmax (Q pre-scaled
// by 0.125*log2e; |scores| <= ~22 in log2 domain -> fp32-safe, precision
// identical to max-subtracted form).
// vs attn3 (82 us): (1) K/V staging register-double-buffered — tile t+1's 8
// global_load_dwordx4 issue right after tile t's staging barrier; their vmcnt
// drain happens at tile t+1's ds_write, hidden behind a full tile of compute.
// (2) P gets a dedicated wave-private LDS region (no K overlay) -> the
// mid-tile barrier disappears: 2 barriers/tile instead of 3. P write->read is
// wave-local (validated pattern since R4).
// LDS: K 18.4KB + V^T 17.4KB + P 34.8KB = 70.7KB -> 2 blocks/CU (grid 512).
// ---------------------------------------------------------------------------
__global__ __launch_bounds__(256) void attn5(
    const unsigned short* __restrict__ qkv,   // Q plane at 0, K plane at PL
    const unsigned short* __restrict__ vt_g,  // [32][64][2048]
    unsigned short* __restrict__ ab) {
  constexpr size_t PL = (size_t)4096 * 1024;
  const int qt = blockIdx.x, bh = blockIdx.y;
  const int b = bh >> 4, h = bh & 15;

  __shared__ unsigned short kl[128 * 72];     // K tile [kv][dk]
  __shared__ unsigned short vtl[64 * 136];    // V^T tile [d][kv]
  __shared__ unsigned short pl[4][32 * 136];  // wave-private P [32 q][128 kv]

  const int tid = threadIdx.x;
  const int wave = tid >> 6, lane = tid & 63;
  const int quad = lane >> 4, l16 = lane & 15;
  const int qb = quad * 20;                   // shfl base: quad*16 + quad*4
  unsigned short* Pw = pl[wave];

  const unsigned short* Kp = qkv + PL + ((size_t)b * 2048) * 1024 + h * 64;
  const unsigned short* Vt = vt_g + (size_t)bh * 64 * 2048;

  // Q fragments in registers: half hf -> q row = qt*128 + wave*32 + hf*16 + l16
  bf16x8 qf[2][2];
#pragma unroll
  for (int hf = 0; hf < 2; ++hf) {
    const unsigned short* qrow =
        qkv + (size_t)(b * 2048 + qt * 128 + wave * 32 + hf * 16 + l16) * 1024 +
        h * 64;
    union { uint4 u; bf16x8 bv; } c;
    c.u = *(const uint4*)(qrow + quad * 8);       qf[hf][0] = c.bv;
    c.u = *(const uint4*)(qrow + 32 + quad * 8);  qf[hf][1] = c.bv;
  }

  // staging indices (thread-fixed): K row c>>3, chunk (c&7)*8;
  //                                 V row c>>4, chunk (c&15)*8  (c=it*256+tid)
  uint4 kreg[4], vreg[4];
#pragma unroll
  for (int it = 0; it < 4; ++it) {   // prologue: prefetch tile 0
    const int c = it * 256 + tid;
    kreg[it] = *(const uint4*)(Kp + (size_t)(c >> 3) * 1024 + (c & 7) * 8);
    vreg[it] = *(const uint4*)(Vt + (size_t)(c >> 4) * 2048 + (c & 15) * 8);
  }

  f32x4 o_acc[2][4] = {};
  float l_part[2] = {0.0f, 0.0f};

  for (int kv0 = 0; kv0 < 2048; kv0 += 128) {
    __syncthreads();   // all waves done reading kl/vtl of the previous tile
#pragma unroll
    for (int it = 0; it < 4; ++it) {  // ds_write waits the prefetch vmcnt here
      const int c = it * 256 + tid;
      *(uint4*)&kl[(c >> 3) * 72 + (c & 7) * 8] = kreg[it];
      *(uint4*)&vtl[(c >> 4) * 136 + (c & 15) * 8] = vreg[it];
    }
    __syncthreads();   // staging visible to all waves

    if (kv0 + 128 < 2048) {   // issue next tile's loads; drained next iter
      const int nkv = kv0 + 128;
#pragma unroll
      for (int it = 0; it < 4; ++it) {
        const int c = it * 256 + tid;
        kreg[it] =
            *(const uint4*)(Kp + (size_t)(nkv + (c >> 3)) * 1024 + (c & 7) * 8);
        vreg[it] =
            *(const uint4*)(Vt + (size_t)(c >> 4) * 2048 + nkv + (c & 15) * 8);
      }
    }

    // S^T[kv][q]: A = K rows (kv), B = Q (q). A-frags shared by both q-halves.
    f32x4 st[2][8] = {};
#pragma unroll
    for (int mb = 0; mb < 8; ++mb) {
      bf16x8 ak0 = ld_frag(&kl[(mb * 16 + l16) * 72 + quad * 8]);
      bf16x8 ak1 = ld_frag(&kl[(mb * 16 + l16) * 72 + 32 + quad * 8]);
#pragma unroll
      for (int hf = 0; hf < 2; ++hf) {
        st[hf][mb] = __builtin_amdgcn_mfma_f32_16x16x32_bf16(
            ak0, qf[hf][0], st[hf][mb], 0, 0, 0);
        st[hf][mb] = __builtin_amdgcn_mfma_f32_16x16x32_bf16(
            ak1, qf[hf][1], st[hf][mb], 0, 0, 0);
      }
    }

    // p = exp2(st); per-lane l; pack into wave-private P (no barrier needed)
#pragma unroll
    for (int hf = 0; hf < 2; ++hf)
#pragma unroll
      for (int mb = 0; mb < 8; ++mb) {
#pragma unroll
        for (int r = 0; r < 4; ++r) {
          const float p = __builtin_amdgcn_exp2f(st[hf][mb][r]);
          st[hf][mb][r] = p;
          l_part[hf] += p;
        }
        uint2 pk;
        pk.x = pk2bf(st[hf][mb][0], st[hf][mb][1]);
        pk.y = pk2bf(st[hf][mb][2], st[hf][mb][3]);
        *(uint2*)&Pw[(hf * 16 + l16) * 136 + mb * 16 + quad * 4] = pk;
      }

    // O += P·V: V^T B-frags read once, used for both q-halves.
#pragma unroll
    for (int ks = 0; ks < 4; ++ks) {
      bf16x8 bvf[4];
#pragma unroll
      for (int nt = 0; nt < 4; ++nt)
        bvf[nt] = ld_frag(&vtl[(nt * 16 + l16) * 136 + ks * 32 + quad * 8]);
#pragma unroll
      for (int hf = 0; hf < 2; ++hf) {
        bf16x8 ap = ld_frag(&Pw[(hf * 16 + l16) * 136 + ks * 32 + quad * 8]);
#pragma unroll
        for (int nt = 0; nt < 4; ++nt)
          o_acc[hf][nt] = __builtin_amdgcn_mfma_f32_16x16x32_bf16(
              ap, bvf[nt], o_acc[hf][nt], 0, 0, 0);
      }
    }
  }

  // reduce l (lanes with same l16 hold disjoint kv of the same q), normalize
#pragma unroll
  for (int hf = 0; hf < 2; ++hf) {
    float lp = l_part[hf];
    lp += __shfl_xor(lp, 16);
    lp += __shfl_xor(lp, 32);
    float lr[4];
#pragma unroll
    for (int r = 0; r < 4; ++r) lr[r] = 1.0f / __shfl(lp, qb + r);
#pragma unroll
    for (int nt = 0; nt < 4; ++nt)
#pragma unroll
      for (int r = 0; r < 4; ++r) {
        const int row = qt * 128 + wave * 32 + hf * 16 + quad * 4 + r;
        ab[((size_t)b * 2048 + row) * 1024 + h * 64 + nt * 16 + l16] =
            f2bf(o_acc[hf][nt][r] * lr[r]);
      }
  }
}

// ---------------------------------------------------------------------------
extern "C" void kernel_launch(void* const* d_in, const int* in_sizes, int n_in,
                              void* d_out, int out_size, void* d_ws,
                              size_t ws_size, hipStream_t stream) {
  const float* x  = (const float*)d_in[0];
  const float* wq = (const float*)d_in[1];
  const float* wk = (const float*)d_in[2];
  const float* wv = (const float*)d_in[3];
  const float* wo = (const float*)d_in[4];
  const float* bo = (const float*)d_in[5];

  constexpr size_t PL = (size_t)4096 * 1024;
  unsigned short* qkv = (unsigned short*)d_ws;   // 3 planes: Q, K, V
  unsigned short* ab  = qkv + 2 * PL;            // overlays dead V plane
  unsigned short* xb  = qkv + 3 * PL;            // x bf16; later vt alias
  unsigned short* vt  = xb;                      // V^T [32][64][2048]
  unsigned short* wqb = qkv + 4 * PL;
  unsigned short* wkb = wqb + 1024 * 1024;
  unsigned short* wvb = wkb + 1024 * 1024;
  unsigned short* wob = wvb + 1024 * 1024;

  const float QSCALE = 0.18033688011112042f;  // 0.125 * log2(e)

  cvt_all<<<dim3(2048, 5), 256, 0, stream>>>(x, wq, wk, wv, wo,
                                             xb, wqb, wkb, wvb, wob);
  gemm_bt<128, false><<<dim3(8, 32, 3), 256, 0, stream>>>(
      xb, wqb, wkb, wvb, nullptr, qkv, QSCALE);
  transpose_v<<<dim3(32, 32), 256, 0, stream>>>(qkv + 2 * PL, vt);
  attn5<<<dim3(16, 32), 256, 0, stream>>>(qkv, vt, ab);
  gemm_bt<64, true><<<dim3(8, 64, 1), 256, 0, stream>>>(
      ab, wob, wob, wob, bo, d_out, 1.0f);
}

// Round 10
// 229.842 us; speedup vs baseline: 1.0477x; 1.0477x over previous
//
#include <hip/hip_runtime.h>
#include <hip/hip_bf16.h>

// ---------------------------------------------------------------------------
// HessianCompatibleMultiHeadAttention on MI355X (gfx950).
// Inputs fp32, output fp32. Internal bf16 MFMA.
// B=2, S=2048, D=1024, H=16, Dk=64.
//   cvt_all:      x, wq, wk, wv, wo  -> bf16
//   gemm_bt<128>: qkv = x_bf @ W^T   (z=0 Q pre-scaled by 0.125*log2e)
//   transpose_v:  V plane -> V^T [bh][64][2048]
//   attn6:        attn3 (R6-proven) + kv-split x2: grid (16,32,2), each block
//                 does half the kv stream (8 tiles); writes raw bf16
//                 O-partials + fp32 l-partials (exactly summable under no-max
//                 exp2 softmax). 1024 blocks -> 3 resident blocks/CU.
//   attn_combine: ab = (O0+O1)/(l0+l1)  (memory-bound, ~25 MB)
//   gemm_bt<64>:  out = ab @ Wo^T + b_o  (fp32 out, 512 blocks)
// Lesson log: attn4 (global-direct frags) latency-bound regression; attn5
// (register prefetch) scratch-spill regression (WRITE_SIZE 212 MB).
// ---------------------------------------------------------------------------

typedef __bf16 bf16x8 __attribute__((ext_vector_type(8)));
typedef float f32x4 __attribute__((ext_vector_type(4)));

__device__ __forceinline__ unsigned short f2bf(float f) {
  union { float f; unsigned int u; } c; c.f = f;
  unsigned int u = c.u;
  return (unsigned short)((u + 0x7FFFu + ((u >> 16) & 1u)) >> 16);
}

__device__ __forceinline__ float b2f(unsigned short u) {
  union { unsigned int u; float f; } c; c.u = ((unsigned int)u) << 16;
  return c.f;
}

// pack two fp32 -> two bf16 (round-half-up) in 3 VALU ops
__device__ __forceinline__ unsigned int pk2bf(float a, float b) {
  union { float f; unsigned int u; } x, y;
  x.f = a; y.f = b;
  return __builtin_amdgcn_perm(y.u + 0x8000u, x.u + 0x8000u, 0x07060302u);
}

__device__ __forceinline__ bf16x8 ld_frag(const unsigned short* p) {
  union { uint4 u; bf16x8 b; } c;
  c.u = *(const uint4*)p;   // 16B aligned -> ds_read_b128
  return c.b;
}

__device__ __forceinline__ uint4 cvt8(const float* __restrict__ p) {
  float4 a = *(const float4*)p;
  float4 b = *(const float4*)(p + 4);
  union { uint4 u; unsigned short s[8]; } r;
  r.s[0] = f2bf(a.x); r.s[1] = f2bf(a.y); r.s[2] = f2bf(a.z); r.s[3] = f2bf(a.w);
  r.s[4] = f2bf(b.x); r.s[5] = f2bf(b.y); r.s[6] = f2bf(b.z); r.s[7] = f2bf(b.w);
  return r.u;
}

// async global->LDS, 16B per lane (lds dest = wave-uniform base + lane*16)
typedef __attribute__((address_space(1))) const unsigned int as1_u32;
typedef __attribute__((address_space(3))) unsigned int as3_u32;
__device__ __forceinline__ void async16(const unsigned short* g,
                                        unsigned short* l) {
  __builtin_amdgcn_global_load_lds(
      (as1_u32*)(unsigned long long)g,
      (as3_u32*)(unsigned int)(unsigned long long)l, 16, 0, 0);
}

// ---------------------------------------------------------------------------
// fp32 -> bf16 conversion (memory-bound). grid (2048, 5).
// ---------------------------------------------------------------------------
__global__ __launch_bounds__(256) void cvt_all(
    const float* __restrict__ s0, const float* __restrict__ s1,
    const float* __restrict__ s2, const float* __restrict__ s3,
    const float* __restrict__ s4,
    unsigned short* __restrict__ d0, unsigned short* __restrict__ d1,
    unsigned short* __restrict__ d2, unsigned short* __restrict__ d3,
    unsigned short* __restrict__ d4) {
  const float* srcs[5] = {s0, s1, s2, s3, s4};
  unsigned short* dsts[5] = {d0, d1, d2, d3, d4};
  const int ns[5] = {4194304, 1048576, 1048576, 1048576, 1048576};
  const int y = blockIdx.y;
  const int idx = (blockIdx.x * 256 + threadIdx.x) * 8;
  if (idx >= ns[y]) return;
  *(uint4*)(dsts[y] + idx) = cvt8(srcs[y] + idx);
}

// ---------------------------------------------------------------------------
// GEMM [R6-proven]: C[m][n] = scl * sum_k A[m][k] W[n][k] (+ bias[n]).
// N=1024, K=1024. BN=128, BK=32, 256 thr.
// BM=128: 4 waves 2x2 of 64x64 (qkv path, grid (8,32,3)).
// BM=64:  4 waves 1x4, wave = 64m x 32n (out path, grid (8,64,1)).
// Staging: global_load_lds w=16; unpadded LDS [row][32], k-chunk XOR swizzle.
// ---------------------------------------------------------------------------
template <int BM, bool OUT_F32>
__global__ __launch_bounds__(256) void gemm_bt(
    const unsigned short* __restrict__ A,
    const unsigned short* __restrict__ w0,
    const unsigned short* __restrict__ w1,
    const unsigned short* __restrict__ w2,
    const float* __restrict__ bias,
    void* __restrict__ outraw, float z0scale) {
  constexpr int NT = (BM == 128) ? 4 : 2;
  const int z = blockIdx.z;
  const unsigned short* W = (z == 0) ? w0 : ((z == 1) ? w1 : w2);
  const float scl = (z == 0) ? z0scale : 1.0f;

  __shared__ unsigned short a_lds[BM * 32];
  __shared__ unsigned short b_lds[128 * 32];

  const int tid = threadIdx.x;
  const int wave = tid >> 6, lane = tid & 63;
  const int quad = lane >> 4, l16 = lane & 15;
  const int wm = (BM == 128) ? (wave >> 1) * 64 : 0;
  const int wn = (BM == 128) ? (wave & 1) * 64 : wave * 32;
  const int bm = blockIdx.y * BM, bn = blockIdx.x * 128;

  const int rl = lane >> 2;   // 0..15
  const int kc = (lane & 3) ^ (rl & 3) ^ ((rl >> 2) & 3);
  const int arow = (BM == 128) ? (wave * 32 + rl) : (wave * 16 + rl);
  const unsigned short* ga = A + (size_t)(bm + arow) * 1024 + kc * 8;
  const unsigned short* gb = W + (size_t)(bn + wave * 32 + rl) * 1024 + kc * 8;
  unsigned short* la = &a_lds[((BM == 128) ? wave * 32 : wave * 16) * 32];
  unsigned short* lb = &b_lds[wave * 32 * 32];

  const int rsw8 = ((l16 & 3) ^ ((l16 >> 2) & 3)) * 8;

  f32x4 acc[4][NT] = {};

  for (int k0 = 0; k0 < 1024; k0 += 32) {
    async16(ga, la);
    if (BM == 128) async16(ga + 16 * 1024, la + 16 * 32);
    async16(gb, lb);
    async16(gb + 16 * 1024, lb + 16 * 32);
    ga += 32; gb += 32;
    __syncthreads();

    bf16x8 af[4], bfr[NT];
#pragma unroll
    for (int t = 0; t < 4; ++t)
      af[t] = ld_frag(&a_lds[(wm + t * 16 + l16) * 32 + ((quad * 8) ^ rsw8)]);
#pragma unroll
    for (int t = 0; t < NT; ++t)
      bfr[t] = ld_frag(&b_lds[(wn + t * 16 + l16) * 32 + ((quad * 8) ^ rsw8)]);
#pragma unroll
    for (int mt = 0; mt < 4; ++mt)
#pragma unroll
      for (int nt = 0; nt < NT; ++nt)
        acc[mt][nt] = __builtin_amdgcn_mfma_f32_16x16x32_bf16(
            af[mt], bfr[nt], acc[mt][nt], 0, 0, 0);
    __syncthreads();
  }

  // Epilogue: C/D layout col = lane&15, row = quad*4 + reg  [m89-verified]
#pragma unroll
  for (int nt = 0; nt < NT; ++nt) {
    const int n = bn + wn + nt * 16 + l16;
    const float bv = bias ? bias[n] : 0.0f;
#pragma unroll
    for (int mt = 0; mt < 4; ++mt)
#pragma unroll
      for (int r = 0; r < 4; ++r) {
        const int m = bm + wm + mt * 16 + quad * 4 + r;
        const float v = acc[mt][nt][r] * scl + bv;
        if (OUT_F32)
          ((float*)outraw)[(size_t)z * 4096 * 1024 + (size_t)m * 1024 + n] = v;
        else
          ((unsigned short*)outraw)[(size_t)z * 4096 * 1024 +
                                    (size_t)m * 1024 + n] = f2bf(v);
      }
  }
}

// ---------------------------------------------------------------------------
// V plane [4096][1024] -> V^T [32 bh][64 d][2048 s]. grid (32, 32).
// ---------------------------------------------------------------------------
__global__ __launch_bounds__(256) void transpose_v(
    const unsigned short* __restrict__ v, unsigned short* __restrict__ vt) {
  const int st0 = blockIdx.x * 64;
  const int bh = blockIdx.y, b = bh >> 4, h = bh & 15;
  __shared__ unsigned short t[64 * 72];
  const int tid = threadIdx.x;
#pragma unroll
  for (int it = 0; it < 2; ++it) {
    const int c = it * 256 + tid;
    const int row = c >> 3, c8 = (c & 7) * 8;
    *(uint4*)&t[row * 72 + c8] =
        *(const uint4*)(v + (size_t)(b * 2048 + st0 + row) * 1024 + h * 64 + c8);
  }
  __syncthreads();
#pragma unroll
  for (int it = 0; it < 2; ++it) {
    const int c = it * 256 + tid;
    const int drow = c >> 3, s8 = (c & 7) * 8;
    union { uint4 u; unsigned short e[8]; } o;
#pragma unroll
    for (int j = 0; j < 8; ++j) o.e[j] = t[(s8 + j) * 72 + drow];
    *(uint4*)(vt + ((size_t)bh * 64 + drow) * 2048 + st0 + s8) = o.u;
  }
}

// ---------------------------------------------------------------------------
// Flash attention v6 = R6-proven attn3 + kv-split x2.
// q-tile 128, S^T form, no-max exp2 softmax (Q pre-scaled by 0.125*log2e;
// |scores| <= ~22 in log2 domain -> fp32-safe; partials exactly summable).
// Grid (16 qt, 32 bh, 2 kvh): block handles kv in [kvh*1024, kvh*1024+1024),
// 8 tiles of 128. Writes raw bf16 O-partial (no normalize) + fp32 l-partial.
// LDS 52224 B -> 3 resident blocks/CU with the 1024-block grid.
// ---------------------------------------------------------------------------
__global__ __launch_bounds__(256) void attn6(
    const unsigned short* __restrict__ qkv,   // Q plane at 0, K plane at PL
    const unsigned short* __restrict__ vt_g,  // [32][64][2048]
    unsigned short* __restrict__ opart,       // [2][4096][1024] bf16
    float* __restrict__ lpart) {              // [2][32][2048]
  constexpr size_t PL = (size_t)4096 * 1024;
  const int qt = blockIdx.x, bh = blockIdx.y, kvh = blockIdx.z;
  const int b = bh >> 4, h = bh & 15;
  const int kvbase = kvh * 1024;

  __shared__ unsigned short kp[128 * 136];  // K tile (stride 72); P (stride 136)
  __shared__ unsigned short vtl[64 * 136];  // V^T tile [d][kv]

  const int tid = threadIdx.x;
  const int wave = tid >> 6, lane = tid & 63;
  const int quad = lane >> 4, l16 = lane & 15;

  const unsigned short* Kp =
      qkv + PL + ((size_t)b * 2048 + kvbase) * 1024 + h * 64;
  const unsigned short* Vt = vt_g + (size_t)bh * 64 * 2048 + kvbase;

  // Q fragments in registers: half hf -> q row = qt*128 + wave*32 + hf*16 + l16
  bf16x8 qf[2][2];
#pragma unroll
  for (int hf = 0; hf < 2; ++hf) {
    const unsigned short* qrow =
        qkv + (size_t)(b * 2048 + qt * 128 + wave * 32 + hf * 16 + l16) * 1024 +
        h * 64;
    union { uint4 u; bf16x8 bv; } c;
    c.u = *(const uint4*)(qrow + quad * 8);       qf[hf][0] = c.bv;
    c.u = *(const uint4*)(qrow + 32 + quad * 8);  qf[hf][1] = c.bv;
  }

  f32x4 o_acc[2][4] = {};
  float l_part[2] = {0.0f, 0.0f};

  for (int kv0 = 0; kv0 < 1024; kv0 += 128) {
    __syncthreads();  // prior PV reads done -> restage safe
#pragma unroll
    for (int it = 0; it < 4; ++it) {
      const int c = it * 256 + tid;
      const int kr = c >> 3, kc = (c & 7) * 8;
      *(uint4*)&kp[kr * 72 + kc] =
          *(const uint4*)(Kp + (size_t)(kv0 + kr) * 1024 + kc);
      const int vr = c >> 4, vc = (c & 15) * 8;
      *(uint4*)&vtl[vr * 136 + vc] =
          *(const uint4*)(Vt + (size_t)vr * 2048 + kv0 + vc);
    }
    __syncthreads();

    // S^T[kv][q]: A = K rows (kv), B = Q (q). A-frags shared by both q-halves.
    f32x4 st[2][8] = {};
#pragma unroll
    for (int mb = 0; mb < 8; ++mb) {
      bf16x8 ak0 = ld_frag(&kp[(mb * 16 + l16) * 72 + quad * 8]);
      bf16x8 ak1 = ld_frag(&kp[(mb * 16 + l16) * 72 + 32 + quad * 8]);
#pragma unroll
      for (int hf = 0; hf < 2; ++hf) {
        st[hf][mb] = __builtin_amdgcn_mfma_f32_16x16x32_bf16(
            ak0, qf[hf][0], st[hf][mb], 0, 0, 0);
        st[hf][mb] = __builtin_amdgcn_mfma_f32_16x16x32_bf16(
            ak1, qf[hf][1], st[hf][mb], 0, 0, 0);
      }
    }

    // p = exp2(st); accumulate l per-lane per half
#pragma unroll
    for (int hf = 0; hf < 2; ++hf)
#pragma unroll
      for (int mb = 0; mb < 8; ++mb)
#pragma unroll
        for (int r = 0; r < 4; ++r) {
          const float p = __builtin_amdgcn_exp2f(st[hf][mb][r]);
          st[hf][mb][r] = p;
          l_part[hf] += p;
        }

    __syncthreads();  // all K reads done -> P may overlay
#pragma unroll
    for (int hf = 0; hf < 2; ++hf)
#pragma unroll
      for (int mb = 0; mb < 8; ++mb) {
        uint2 pk;
        pk.x = pk2bf(st[hf][mb][0], st[hf][mb][1]);
        pk.y = pk2bf(st[hf][mb][2], st[hf][mb][3]);
        *(uint2*)&kp[(wave * 32 + hf * 16 + l16) * 136 + mb * 16 + quad * 4] =
            pk;
      }

    // O += P·V: B-frags (V^T) read once, used for both halves.
#pragma unroll
    for (int ks = 0; ks < 4; ++ks) {
      bf16x8 bvf[4];
#pragma unroll
      for (int nt = 0; nt < 4; ++nt)
        bvf[nt] = ld_frag(&vtl[(nt * 16 + l16) * 136 + ks * 32 + quad * 8]);
#pragma unroll
      for (int hf = 0; hf < 2; ++hf) {
        bf16x8 ap =
            ld_frag(&kp[(wave * 32 + hf * 16 + l16) * 136 + ks * 32 + quad * 8]);
#pragma unroll
        for (int nt = 0; nt < 4; ++nt)
          o_acc[hf][nt] = __builtin_amdgcn_mfma_f32_16x16x32_bf16(
              ap, bvf[nt], o_acc[hf][nt], 0, 0, 0);
      }
    }
  }

  // epilogue: write RAW partials (no normalize). l reduced across quads
  // (lanes with same l16 hold disjoint kv of the same q).
  unsigned short* Op = opart + (size_t)kvh * PL;
#pragma unroll
  for (int hf = 0; hf < 2; ++hf) {
    float lp = l_part[hf];
    lp += __shfl_xor(lp, 16);
    lp += __shfl_xor(lp, 32);
    const int q = qt * 128 + wave * 32 + hf * 16 + l16;
    if (quad == 0)
      lpart[((size_t)kvh * 32 + bh) * 2048 + q] = lp;
#pragma unroll
    for (int nt = 0; nt < 4; ++nt)
#pragma unroll
      for (int r = 0; r < 4; ++r) {
        const int row = qt * 128 + wave * 32 + hf * 16 + quad * 4 + r;
        Op[((size_t)b * 2048 + row) * 1024 + h * 64 + nt * 16 + l16] =
            f2bf(o_acc[hf][nt][r]);
      }
  }
}

// ---------------------------------------------------------------------------
// ab = (O0 + O1) / (l0 + l1).  grid 2048 x 256 thr; 8 elems/thread.
// ---------------------------------------------------------------------------
__global__ __launch_bounds__(256) void attn_combine(
    const unsigned short* __restrict__ opart,  // [2][4096][1024]
    const float* __restrict__ lpart,           // [2][32][2048]
    unsigned short* __restrict__ ab) {
  constexpr size_t PL = (size_t)4096 * 1024;
  const int gid = blockIdx.x * 256 + threadIdx.x;
  const int s = gid >> 7;              // token row 0..4095
  const int c = (gid & 127) * 8;       // col 0..1016
  const int b = s >> 11, q = s & 2047, h = c >> 6;
  const size_t li = (size_t)(b * 16 + h) * 2048 + q;
  const float inv = 1.0f / (lpart[li] + lpart[32 * 2048 + li]);
  const size_t off = (size_t)s * 1024 + c;
  union { uint4 u; unsigned short e[8]; } a, bv, o;
  a.u = *(const uint4*)(opart + off);
  bv.u = *(const uint4*)(opart + PL + off);
#pragma unroll
  for (int j = 0; j < 8; j += 2) {
    const float v0 = (b2f(a.e[j]) + b2f(bv.e[j])) * inv;
    const float v1 = (b2f(a.e[j + 1]) + b2f(bv.e[j + 1])) * inv;
    *(unsigned int*)&o.e[j] = pk2bf(v0, v1);
  }
  *(uint4*)(ab + off) = o.u;
}

// ---------------------------------------------------------------------------
extern "C" void kernel_launch(void* const* d_in, const int* in_sizes, int n_in,
                              void* d_out, int out_size, void* d_ws,
                              size_t ws_size, hipStream_t stream) {
  const float* x  = (const float*)d_in[0];
  const float* wq = (const float*)d_in[1];
  const float* wk = (const float*)d_in[2];
  const float* wv = (const float*)d_in[3];
  const float* wo = (const float*)d_in[4];
  const float* bo = (const float*)d_in[5];

  constexpr size_t PL = (size_t)4096 * 1024;
  unsigned short* qkv = (unsigned short*)d_ws;   // 3 planes: Q, K, V
  unsigned short* ab  = qkv + 2 * PL;            // overlays dead V plane
  unsigned short* xb  = qkv + 3 * PL;            // x bf16; later vt alias
  unsigned short* vt  = xb;                      // V^T [32][64][2048]
  unsigned short* wqb = qkv + 4 * PL;
  unsigned short* wkb = wqb + 1024 * 1024;
  unsigned short* wvb = wkb + 1024 * 1024;
  unsigned short* wob = wvb + 1024 * 1024;
  unsigned short* opart = wob + 1024 * 1024;     // [2][4096][1024] bf16
  float* lpart = (float*)(opart + 2 * PL);       // [2][32][2048] fp32

  const float QSCALE = 0.18033688011112042f;  // 0.125 * log2(e)

  cvt_all<<<dim3(2048, 5), 256, 0, stream>>>(x, wq, wk, wv, wo,
                                             xb, wqb, wkb, wvb, wob);
  gemm_bt<128, false><<<dim3(8, 32, 3), 256, 0, stream>>>(
      xb, wqb, wkb, wvb, nullptr, qkv, QSCALE);
  transpose_v<<<dim3(32, 32), 256, 0, stream>>>(qkv + 2 * PL, vt);
  attn6<<<dim3(16, 32, 2), 256, 0, stream>>>(qkv, vt, opart, lpart);
  attn_combine<<<dim3(2048), 256, 0, stream>>>(opart, lpart, ab);
  gemm_bt<64, true><<<dim3(8, 64, 1), 256, 0, stream>>>(
      ab, wob, wob, wob, bo, d_out, 1.0f);
}